// Round 8
// baseline (290.608 us; speedup 1.0000x reference)
//
#include <hip/hip_runtime.h>
#include <hip/hip_fp16.h>

// ---------------------------------------------------------------------------
// GCN pipeline v8: fused layer with VGPR-pinned W (asm anti-remat) and
// 2-node-per-wave ILP. 10 dispatches.
// N=50000 nodes, E=800000 edges, H=F=64, G=512 graphs, C=10 classes
// ---------------------------------------------------------------------------

// Single-block: detect whether mask is bytes (some word >1) or int32 0/1.
__global__ void k_detect(const unsigned int* __restrict__ m, int n_ints,
                         int* __restrict__ flag) {
  __shared__ int found;
  if (threadIdx.x == 0) found = 0;
  __syncthreads();
  int loc = 0;
  for (int i = threadIdx.x; i < n_ints; i += blockDim.x)
    if (m[i] > 1u) loc = 1;
  if (loc) found = 1;
  __syncthreads();
  if (threadIdx.x == 0) *flag = found;
}

// maskf + zero cnt + init gs/ge + convert x -> fp16 xh (grid covers N*64)
__global__ void k_prep(const float* __restrict__ x, __half* __restrict__ xh,
                       const void* __restrict__ mraw, const int* __restrict__ flag,
                       float* __restrict__ maskf, int* __restrict__ cnt,
                       int* __restrict__ gs, int* __restrict__ ge,
                       long total, int N, int G) {
  long idx = (long)blockIdx.x * blockDim.x + threadIdx.x;
  if (idx < total) xh[idx] = __float2half_rn(x[idx]);
  if (idx < G) { gs[idx] = 0x7fffffff; ge[idx] = -1; }
  if (idx < N) {
    float v;
    if (*flag) v = (float)((const unsigned char*)mraw)[idx];
    else       v = (float)((const int*)mraw)[idx];
    maskf[idx] = v;
    cnt[idx] = 0;
  }
}

// cnt[d] += 1 for each edge with both endpoints kept
__global__ void k_cnt(const int* __restrict__ src, const int* __restrict__ dst,
                      const float* __restrict__ maskf, int* __restrict__ cnt, int E) {
  int e = blockIdx.x * blockDim.x + threadIdx.x;
  if (e >= E) return;
  int s = src[e], d = dst[e];
  if (maskf[s] != 0.f && maskf[d] != 0.f) atomicAdd(&cnt[d], 1);
}

// dinv + slots(=cnt+kept) scan; slots stashed in cursor[] for scan3
__global__ void k_scan1(const int* __restrict__ cnt, const float* __restrict__ maskf,
                        float* __restrict__ dinv, int* __restrict__ off,
                        int* __restrict__ cursor, int* __restrict__ bsum, int N) {
  __shared__ int s[256];
  int i = blockIdx.x * 256 + threadIdx.x;
  int c = (i < N) ? cnt[i] : 0;
  float mk = (i < N) ? maskf[i] : 0.f;
  float dsum = (float)c + mk;
  if (i < N) dinv[i] = (dsum > 0.f) ? rsqrtf(dsum) : 0.f;
  int v = c + (mk != 0.f ? 1 : 0);  // slots incl. self-loop
  if (i < N) cursor[i] = v;         // stash slots
  s[threadIdx.x] = v;
  __syncthreads();
#pragma unroll
  for (int d = 1; d < 256; d <<= 1) {
    int t = (threadIdx.x >= d) ? s[threadIdx.x - d] : 0;
    __syncthreads();
    s[threadIdx.x] += t;
    __syncthreads();
  }
  if (i < N) off[i] = s[threadIdx.x] - v;
  if (threadIdx.x == 255) bsum[blockIdx.x] = s[255];
}

// finalize offsets; offcnt=(off,slots); write self-loop CSR entry; cursor=off+1
// for kept nodes; per-graph bounds via sorted-batch boundary detection.
__global__ void k_scan3(const int* __restrict__ off_loc, const int* __restrict__ bsum,
                        int nb, int* __restrict__ cursor, int2* __restrict__ offcnt,
                        int2* __restrict__ csr, const float* __restrict__ dinv,
                        const int* __restrict__ batch,
                        int* __restrict__ gs, int* __restrict__ ge, int N) {
  __shared__ int s[256];
  __shared__ int prefix;
  int v = (threadIdx.x < nb) ? bsum[threadIdx.x] : 0;
  s[threadIdx.x] = v;
  __syncthreads();
#pragma unroll
  for (int d = 1; d < 256; d <<= 1) {
    int t = (threadIdx.x >= d) ? s[threadIdx.x - d] : 0;
    __syncthreads();
    s[threadIdx.x] += t;
    __syncthreads();
  }
  if (threadIdx.x == blockIdx.x) prefix = s[threadIdx.x] - v;  // exclusive
  __syncthreads();
  int i = blockIdx.x * 256 + threadIdx.x;
  if (i >= N) return;
  int o = off_loc[i] + prefix;
  int slots = cursor[i];  // stashed by scan1
  offcnt[i] = make_int2(o, slots);
  float di = dinv[i];
  if (di != 0.f) {
    csr[o] = make_int2(i, __float_as_int(di * di));  // self-loop entry
    cursor[i] = o + 1;
  } else {
    cursor[i] = o;
  }
  int b = batch[i];
  if (i == 0 || batch[i - 1] != b) gs[b] = i;
  if (i == N - 1 || batch[i + 1] != b) ge[b] = i;
}

// Fill CSR: (src, weight) per kept edge, grouped by dst.
__global__ void k_fill(const int* __restrict__ src, const int* __restrict__ dst,
                       const float* __restrict__ dinv, int* __restrict__ cursor,
                       int2* __restrict__ csr, int E) {
  int e = blockIdx.x * blockDim.x + threadIdx.x;
  if (e >= E) return;
  int s = src[e], d = dst[e];
  float ws = dinv[s], wd = dinv[d];
  if (ws != 0.f && wd != 0.f) {
    int p = atomicAdd(&cursor[d], 1);
    csr[p] = make_int2(s, __float_as_int(ws * wd));
  }
}

#define GATHER8(ACC0, ACC1, CE, S, WV)                                 \
  {                                                                    \
    const float4 raw = *(const float4*)&Hq[(long)(S) * 64];            \
    const __half2* hp = (const __half2*)&raw;                          \
    const float2 f0 = __half22float2(hp[0]);                           \
    const float2 f1 = __half22float2(hp[1]);                           \
    const float2 f2 = __half22float2(hp[2]);                           \
    const float2 f3 = __half22float2(hp[3]);                           \
    ACC0.x = fmaf(f0.x, WV, ACC0.x);                                   \
    ACC0.y = fmaf(f0.y, WV, ACC0.y);                                   \
    ACC0.z = fmaf(f1.x, WV, ACC0.z);                                   \
    ACC0.w = fmaf(f1.y, WV, ACC0.w);                                   \
    ACC1.x = fmaf(f2.x, WV, ACC1.x);                                   \
    ACC1.y = fmaf(f2.y, WV, ACC1.y);                                   \
    ACC1.z = fmaf(f3.x, WV, ACC1.z);                                   \
    ACC1.w = fmaf(f3.y, WV, ACC1.w);                                   \
  }

// butterfly-reduce 8 floats across the 8 edge-groups
#define BFLY(A0, A1)                                                   \
  _Pragma("unroll") for (int m = 8; m <= 32; m <<= 1) {                \
    A0.x += __shfl_xor(A0.x, m); A0.y += __shfl_xor(A0.y, m);          \
    A0.z += __shfl_xor(A0.z, m); A0.w += __shfl_xor(A0.w, m);          \
    A1.x += __shfl_xor(A1.x, m); A1.y += __shfl_xor(A1.y, m);          \
    A1.z += __shfl_xor(A1.z, m); A1.w += __shfl_xor(A1.w, m);          \
  }

// Fused layer, 2 nodes per wave iteration (grid-stride).
//   agg[0:64] = sum_{e in csr[d]} w_e * Hh[src_e][:]   (self-loop is an entry)
//   z[lane]   = relu( sum_k agg[k]*W[k][lane] + b[lane] )
// W column per lane is PINNED in VGPRs via volatile asm (blocks remat).
template <bool HALFOUT>
__global__ __launch_bounds__(256, 4) void k_agg_gemm(const __half* __restrict__ Hh,
                                                     const int2* __restrict__ offcnt,
                                                     const int2* __restrict__ csr,
                                                     const float* __restrict__ W,
                                                     const float* __restrict__ b,
                                                     void* __restrict__ out, int N) {
  const int lane = threadIdx.x & 63;
  const int wid = threadIdx.x >> 6;
  float wcol[64];
#pragma unroll
  for (int k = 0; k < 64; ++k) {
    wcol[k] = W[k * 64 + lane];
    asm volatile("" : "+v"(wcol[k]));  // pin: block rematerialization
  }
  const float bl = b[lane];
  const int grp = lane >> 3;   // which edge of the octet
  const int q = lane & 7;      // column group: cols 8q..8q+7
  const __half* __restrict__ Hq = Hh + q * 8;

  const int wave_gid = blockIdx.x * 4 + wid;
  const int n_waves = gridDim.x * 4;

  for (int d0 = wave_gid * 2; d0 < N; d0 += n_waves * 2) {
    const int d1 = d0 + 1;
    const int2 oc0 = offcnt[d0];
    const int2 oc1 = (d1 < N) ? offcnt[d1] : make_int2(0, 0);
    const int n0 = oc0.y, n1 = oc1.y;
    if ((n0 | n1) == 0) continue;
    float4 a0x = make_float4(0.f, 0.f, 0.f, 0.f);
    float4 a0y = make_float4(0.f, 0.f, 0.f, 0.f);
    float4 a1x = make_float4(0.f, 0.f, 0.f, 0.f);
    float4 a1y = make_float4(0.f, 0.f, 0.f, 0.f);
    int done0 = 0, done1 = 0;
    while (done0 < n0 || done1 < n1) {
      const int c0 = max(min(n0 - done0, 64), 0);
      const int c1 = max(min(n1 - done1, 64), 0);
      int2 e0 = (lane < c0) ? csr[oc0.x + done0 + lane] : make_int2(0, 0);
      int2 e1 = (lane < c1) ? csr[oc1.x + done1 + lane] : make_int2(0, 0);
      const int r0 = (c0 + 7) & ~7;
      const int r1 = (c1 + 7) & ~7;
      const int r = max(r0, r1);
      for (int i = 0; i < r; i += 8) {
        const int j = i + grp;
        if (i < r0) {
          const int s = __shfl(e0.x, j);
          const float w = __int_as_float(__shfl(e0.y, j));
          GATHER8(a0x, a0y, e0, s, w);
        }
        if (i < r1) {
          const int s = __shfl(e1.x, j);
          const float w = __int_as_float(__shfl(e1.y, j));
          GATHER8(a1x, a1y, e1, s, w);
        }
      }
      done0 += c0;
      done1 += c1;
    }
    // node 0
    if (n0 > 0) {
      BFLY(a0x, a0y);
      float z0 = bl, z1 = 0.f;
#pragma unroll
      for (int k = 0; k < 64; k += 2) {
        const int r0_ = k & 7;
        float c0_;
        if (r0_ == 0) c0_ = a0x.x; else if (r0_ == 1) c0_ = a0x.y;
        else if (r0_ == 2) c0_ = a0x.z; else if (r0_ == 3) c0_ = a0x.w;
        else if (r0_ == 4) c0_ = a0y.x; else if (r0_ == 5) c0_ = a0y.y;
        else if (r0_ == 6) c0_ = a0y.z; else c0_ = a0y.w;
        const int r1_ = (k + 1) & 7;
        float c1_;
        if (r1_ == 0) c1_ = a0x.x; else if (r1_ == 1) c1_ = a0x.y;
        else if (r1_ == 2) c1_ = a0x.z; else if (r1_ == 3) c1_ = a0x.w;
        else if (r1_ == 4) c1_ = a0y.x; else if (r1_ == 5) c1_ = a0y.y;
        else if (r1_ == 6) c1_ = a0y.z; else c1_ = a0y.w;
        z0 = fmaf(__shfl(c0_, k >> 3), wcol[k], z0);
        z1 = fmaf(__shfl(c1_, (k + 1) >> 3), wcol[k + 1], z1);
      }
      const float z = fmaxf(z0 + z1, 0.f);
      if (HALFOUT) ((__half*)out)[(long)d0 * 64 + lane] = __float2half_rn(z);
      else         ((float*)out)[(long)d0 * 64 + lane] = z;
    }
    // node 1
    if (n1 > 0) {
      BFLY(a1x, a1y);
      float z0 = bl, z1 = 0.f;
#pragma unroll
      for (int k = 0; k < 64; k += 2) {
        const int r0_ = k & 7;
        float c0_;
        if (r0_ == 0) c0_ = a1x.x; else if (r0_ == 1) c0_ = a1x.y;
        else if (r0_ == 2) c0_ = a1x.z; else if (r0_ == 3) c0_ = a1x.w;
        else if (r0_ == 4) c0_ = a1y.x; else if (r0_ == 5) c0_ = a1y.y;
        else if (r0_ == 6) c0_ = a1y.z; else c0_ = a1y.w;
        const int r1_ = (k + 1) & 7;
        float c1_;
        if (r1_ == 0) c1_ = a1x.x; else if (r1_ == 1) c1_ = a1x.y;
        else if (r1_ == 2) c1_ = a1x.z; else if (r1_ == 3) c1_ = a1x.w;
        else if (r1_ == 4) c1_ = a1y.x; else if (r1_ == 5) c1_ = a1y.y;
        else if (r1_ == 6) c1_ = a1y.z; else c1_ = a1y.w;
        z0 = fmaf(__shfl(c0_, k >> 3), wcol[k], z0);
        z1 = fmaf(__shfl(c1_, (k + 1) >> 3), wcol[k + 1], z1);
      }
      const float z = fmaxf(z0 + z1, 0.f);
      if (HALFOUT) ((__half*)out)[(long)d1 * 64 + lane] = __float2half_rn(z);
      else         ((float*)out)[(long)d1 * 64 + lane] = z;
    }
  }
}

// Fused: per-graph max-pool over kept nodes -> MLP head -> out[grp][:]
__global__ __launch_bounds__(256) void k_pool_head(
    const float* __restrict__ H, const float* __restrict__ maskf,
    const int* __restrict__ gs, const int* __restrict__ ge,
    const float* __restrict__ fw1, const float* __restrict__ fb1,
    const float* __restrict__ fw2, const float* __restrict__ fb2,
    float* __restrict__ out, int N, int C) {
  __shared__ float sP[4][64];
  __shared__ float sg[64];
  __shared__ float sg2[64];
  const int grp = blockIdx.x;
  const int lane = threadIdx.x & 63, wid = threadIdx.x >> 6;
  const int s = gs[grp], e = ge[grp];
  float v = 0.f;
  if (s <= e) {
    for (int i = s + wid; i <= e; i += 4)
      if (maskf[i] != 0.f) v = fmaxf(v, H[(long)i * 64 + lane]);
  }
  sP[wid][lane] = v;
  __syncthreads();
  if (wid == 0)
    sg[lane] = fmaxf(fmaxf(sP[0][lane], sP[1][lane]), fmaxf(sP[2][lane], sP[3][lane]));
  __syncthreads();
  if (threadIdx.x < 64) {
    const int f = threadIdx.x;
    float acc = fb1[f];
#pragma unroll 8
    for (int k = 0; k < 64; ++k) acc = fmaf(sg[k], fw1[k * 64 + f], acc);
    sg2[f] = fmaxf(acc, 0.f);
  }
  __syncthreads();
  if (threadIdx.x < C) {
    const int c = threadIdx.x;
    float acc = fb2[c];
#pragma unroll 8
    for (int k = 0; k < 64; ++k) acc = fmaf(sg2[k], fw2[k * C + c], acc);
    out[grp * C + c] = acc;
  }
}

extern "C" void kernel_launch(void* const* d_in, const int* in_sizes, int n_in,
                              void* d_out, int out_size, void* d_ws, size_t ws_size,
                              hipStream_t stream) {
  const float* x    = (const float*)d_in[0];
  const int*   ei   = (const int*)d_in[1];
  const int*   batch= (const int*)d_in[2];
  const void*  mraw = d_in[3];
  const float* W1   = (const float*)d_in[4];
  const float* b1   = (const float*)d_in[5];
  const float* W2   = (const float*)d_in[6];
  const float* b2   = (const float*)d_in[7];
  const float* W3   = (const float*)d_in[8];
  const float* b3   = (const float*)d_in[9];
  const float* fw1  = (const float*)d_in[10];
  const float* fb1  = (const float*)d_in[11];
  const float* fw2  = (const float*)d_in[12];
  const float* fb2  = (const float*)d_in[13];
  float* out = (float*)d_out;

  const int N = in_sizes[0] / 64;
  const int E = in_sizes[1] / 2;
  const int C = in_sizes[13];
  const int* src = ei;
  const int* dst = ei + E;
  const int G = out_size / C;

  char* ws = (char*)d_ws;
  size_t off_b = 0;
  auto alloc = [&](size_t bytes) -> void* {
    void* p = ws + off_b;
    off_b += (bytes + 255) & ~(size_t)255;
    return p;
  };
  int*    flag   = (int*)alloc(sizeof(int));
  float*  maskf  = (float*)alloc((size_t)N * 4);
  int*    cnt    = (int*)alloc((size_t)N * 4);
  float*  dinv   = (float*)alloc((size_t)N * 4);
  int*    off    = (int*)alloc((size_t)N * 4);
  int*    cursor = (int*)alloc((size_t)N * 4);
  int*    bsum   = (int*)alloc(256 * 4);
  int*    gs     = (int*)alloc((size_t)G * 4);
  int*    ge     = (int*)alloc((size_t)G * 4);
  int2*   offcnt = (int2*)alloc((size_t)N * 8);
  int2*   csr    = (int2*)alloc(((size_t)E + N) * 8);
  __half* xh     = (__half*)alloc((size_t)N * 64 * 2);
  __half* H1h    = (__half*)alloc((size_t)N * 64 * 2);
  __half* H2h    = (__half*)alloc((size_t)N * 64 * 2);
  float*  H3     = (float*)alloc((size_t)N * 64 * 4);
  (void)ws_size;

  const int nb = (N + 255) / 256;
  const long total = (long)N * 64;
  const int prep_blocks = (int)((total + 255) / 256);

  k_detect<<<1, 1024, 0, stream>>>((const unsigned int*)mraw, N / 4, flag);
  k_prep<<<prep_blocks, 256, 0, stream>>>(x, xh, mraw, flag, maskf, cnt, gs, ge,
                                          total, N, G);
  k_cnt<<<(E + 255) / 256, 256, 0, stream>>>(src, dst, maskf, cnt, E);
  k_scan1<<<nb, 256, 0, stream>>>(cnt, maskf, dinv, off, cursor, bsum, N);
  k_scan3<<<nb, 256, 0, stream>>>(off, bsum, nb, cursor, offcnt, csr, dinv,
                                  batch, gs, ge, N);
  k_fill<<<(E + 255) / 256, 256, 0, stream>>>(src, dst, dinv, cursor, csr, E);

  const int lay_blocks = 1024;  // 4 blocks/CU at 4 waves/SIMD budget
  k_agg_gemm<true ><<<lay_blocks, 256, 0, stream>>>(xh,  offcnt, csr, W1, b1, H1h, N);
  k_agg_gemm<true ><<<lay_blocks, 256, 0, stream>>>(H1h, offcnt, csr, W2, b2, H2h, N);
  k_agg_gemm<false><<<lay_blocks, 256, 0, stream>>>(H2h, offcnt, csr, W3, b3, H3,  N);

  k_pool_head<<<G, 256, 0, stream>>>(H3, maskf, gs, ge, fw1, fb1, fw2, fb2, out, N, C);
}

// Round 9
// 270.206 us; speedup vs baseline: 1.0755x; 1.0755x over previous
//
#include <hip/hip_runtime.h>
#include <hip/hip_fp16.h>

// ---------------------------------------------------------------------------
// GCN pipeline v9: W-first (T=H@W dense, fp16), then light CSR gather with
// fused bias+relu. 13 dispatches.
// N=50000 nodes, E=800000 edges, H=F=64, G=512 graphs, C=10 classes
// ---------------------------------------------------------------------------

// Single-block: detect whether mask is bytes (some word >1) or int32 0/1.
__global__ void k_detect(const unsigned int* __restrict__ m, int n_ints,
                         int* __restrict__ flag) {
  __shared__ int found;
  if (threadIdx.x == 0) found = 0;
  __syncthreads();
  int loc = 0;
  for (int i = threadIdx.x; i < n_ints; i += blockDim.x)
    if (m[i] > 1u) loc = 1;
  if (loc) found = 1;
  __syncthreads();
  if (threadIdx.x == 0) *flag = found;
}

// maskf + zero cnt + init gs/ge
__global__ void k_prep(const void* __restrict__ mraw, const int* __restrict__ flag,
                       float* __restrict__ maskf, int* __restrict__ cnt,
                       int* __restrict__ gs, int* __restrict__ ge, int N, int G) {
  int i = blockIdx.x * blockDim.x + threadIdx.x;
  if (i < G) { gs[i] = 0x7fffffff; ge[i] = -1; }
  if (i >= N) return;
  float v;
  if (*flag) v = (float)((const unsigned char*)mraw)[i];
  else       v = (float)((const int*)mraw)[i];
  maskf[i] = v;
  cnt[i] = 0;
}

// cnt[d] += 1 for each edge with both endpoints kept
__global__ void k_cnt(const int* __restrict__ src, const int* __restrict__ dst,
                      const float* __restrict__ maskf, int* __restrict__ cnt, int E) {
  int e = blockIdx.x * blockDim.x + threadIdx.x;
  if (e >= E) return;
  int s = src[e], d = dst[e];
  if (maskf[s] != 0.f && maskf[d] != 0.f) atomicAdd(&cnt[d], 1);
}

// dinv + slots(=cnt+kept) block-local scan; slots stashed in cursor[]
__global__ void k_scan1(const int* __restrict__ cnt, const float* __restrict__ maskf,
                        float* __restrict__ dinv, int* __restrict__ off,
                        int* __restrict__ cursor, int* __restrict__ bsum, int N) {
  __shared__ int s[256];
  int i = blockIdx.x * 256 + threadIdx.x;
  int c = (i < N) ? cnt[i] : 0;
  float mk = (i < N) ? maskf[i] : 0.f;
  float dsum = (float)c + mk;
  if (i < N) dinv[i] = (dsum > 0.f) ? rsqrtf(dsum) : 0.f;
  int v = c + (mk != 0.f ? 1 : 0);  // slots incl. self-loop
  if (i < N) cursor[i] = v;         // stash slots
  s[threadIdx.x] = v;
  __syncthreads();
#pragma unroll
  for (int d = 1; d < 256; d <<= 1) {
    int t = (threadIdx.x >= d) ? s[threadIdx.x - d] : 0;
    __syncthreads();
    s[threadIdx.x] += t;
    __syncthreads();
  }
  if (i < N) off[i] = s[threadIdx.x] - v;
  if (threadIdx.x == 255) bsum[blockIdx.x] = s[255];
}

// finalize offsets; offcnt=(off,slots); self-loop CSR entry; cursor; bounds.
__global__ void k_scan3(const int* __restrict__ off_loc, const int* __restrict__ bsum,
                        int nb, int* __restrict__ cursor, int2* __restrict__ offcnt,
                        int2* __restrict__ csr, const float* __restrict__ dinv,
                        const int* __restrict__ batch,
                        int* __restrict__ gs, int* __restrict__ ge, int N) {
  __shared__ int s[256];
  __shared__ int prefix;
  int v = (threadIdx.x < nb) ? bsum[threadIdx.x] : 0;
  s[threadIdx.x] = v;
  __syncthreads();
#pragma unroll
  for (int d = 1; d < 256; d <<= 1) {
    int t = (threadIdx.x >= d) ? s[threadIdx.x - d] : 0;
    __syncthreads();
    s[threadIdx.x] += t;
    __syncthreads();
  }
  if (threadIdx.x == blockIdx.x) prefix = s[threadIdx.x] - v;  // exclusive
  __syncthreads();
  int i = blockIdx.x * 256 + threadIdx.x;
  if (i >= N) return;
  int o = off_loc[i] + prefix;
  int slots = cursor[i];  // stashed by scan1
  offcnt[i] = make_int2(o, slots);
  float di = dinv[i];
  if (di != 0.f) {
    csr[o] = make_int2(i, __float_as_int(di * di));  // self-loop entry
    cursor[i] = o + 1;
  } else {
    cursor[i] = o;
  }
  int b = batch[i];
  if (i == 0 || batch[i - 1] != b) gs[b] = i;
  if (i == N - 1 || batch[i + 1] != b) ge[b] = i;
}

// Fill CSR: (src, weight) per kept edge, grouped by dst.
__global__ void k_fill(const int* __restrict__ src, const int* __restrict__ dst,
                       const float* __restrict__ dinv, int* __restrict__ cursor,
                       int2* __restrict__ csr, int E) {
  int e = blockIdx.x * blockDim.x + threadIdx.x;
  if (e >= E) return;
  int s = src[e], d = dst[e];
  float ws = dinv[s], wd = dinv[d];
  if (ws != 0.f && wd != 0.f) {
    int p = atomicAdd(&cursor[d], 1);
    csr[p] = make_int2(s, __float_as_int(ws * wd));
  }
}

// T[r][:] = A[r][:] @ W   (fp16 out, no bias/relu; skips dropped rows)
__global__ __launch_bounds__(256) void k_gemm(const float* __restrict__ A,
                                              const float* __restrict__ dinv,
                                              const float* __restrict__ W,
                                              __half* __restrict__ T, int nrows) {
  const int lane = threadIdx.x & 63;
  const int wid = threadIdx.x >> 6;
  float wcol[64];
#pragma unroll
  for (int k = 0; k < 64; ++k) wcol[k] = W[k * 64 + lane];
  for (int r = blockIdx.x * 4 + wid; r < nrows; r += gridDim.x * 4) {
    if (dinv[r] == 0.f) continue;  // dropped row: never gathered
    const float av = A[(long)r * 64 + lane];
    float acc = 0.f;
#pragma unroll
    for (int k = 0; k < 64; ++k) acc = fmaf(__shfl(av, k), wcol[k], acc);
    T[(long)r * 64 + lane] = __float2half_rn(acc);
  }
}

// H[d][:] = relu( sum_{e in csr[d]} w_e * T[src_e][:] + b )   (f32 out)
// Wave per kept node; 8 edges/iter via 8-lane groups; tiny epilogue.
__global__ __launch_bounds__(256) void k_agg(const __half* __restrict__ Th,
                                             const int2* __restrict__ offcnt,
                                             const int2* __restrict__ csr,
                                             const float* __restrict__ b,
                                             float* __restrict__ H, int N) {
  const int lane = threadIdx.x & 63;
  const int wid = threadIdx.x >> 6;
  const int grp = lane >> 3;   // which edge of the octet
  const int q = lane & 7;      // column group: cols 8q..8q+7
  const __half* __restrict__ Tq = Th + q * 8;
  const float4 bq0 = *(const float4*)&b[q * 8];
  const float4 bq1 = *(const float4*)&b[q * 8 + 4];

  for (int d = blockIdx.x * 4 + wid; d < N; d += gridDim.x * 4) {
    const int2 oc = offcnt[d];
    const int n = oc.y;
    if (n == 0) continue;  // dropped node
    float4 a0 = make_float4(0.f, 0.f, 0.f, 0.f);
    float4 a1 = make_float4(0.f, 0.f, 0.f, 0.f);
    int done = 0;
    while (done < n) {
      const int chunk = min(n - done, 64);
      int2 ce = (lane < chunk) ? csr[oc.x + done + lane] : make_int2(0, 0);
      const int rounds = (chunk + 7) & ~7;
#pragma unroll 2
      for (int i = 0; i < rounds; i += 8) {
        const int j = i + grp;
        const int s = __shfl(ce.x, j);
        const float w = __int_as_float(__shfl(ce.y, j));  // 0 for padded lanes
        const float4 raw = *(const float4*)&Tq[(long)s * 64];
        const __half2* hp = (const __half2*)&raw;
        const float2 f0 = __half22float2(hp[0]);
        const float2 f1 = __half22float2(hp[1]);
        const float2 f2 = __half22float2(hp[2]);
        const float2 f3 = __half22float2(hp[3]);
        a0.x = fmaf(f0.x, w, a0.x);
        a0.y = fmaf(f0.y, w, a0.y);
        a0.z = fmaf(f1.x, w, a0.z);
        a0.w = fmaf(f1.y, w, a0.w);
        a1.x = fmaf(f2.x, w, a1.x);
        a1.y = fmaf(f2.y, w, a1.y);
        a1.z = fmaf(f3.x, w, a1.z);
        a1.w = fmaf(f3.y, w, a1.w);
      }
      done += chunk;
    }
    // butterfly across the 8 edge-groups
#pragma unroll
    for (int m = 8; m <= 32; m <<= 1) {
      a0.x += __shfl_xor(a0.x, m);
      a0.y += __shfl_xor(a0.y, m);
      a0.z += __shfl_xor(a0.z, m);
      a0.w += __shfl_xor(a0.w, m);
      a1.x += __shfl_xor(a1.x, m);
      a1.y += __shfl_xor(a1.y, m);
      a1.z += __shfl_xor(a1.z, m);
      a1.w += __shfl_xor(a1.w, m);
    }
    if (grp == 0) {
      float4 r0, r1;
      r0.x = fmaxf(a0.x + bq0.x, 0.f);
      r0.y = fmaxf(a0.y + bq0.y, 0.f);
      r0.z = fmaxf(a0.z + bq0.z, 0.f);
      r0.w = fmaxf(a0.w + bq0.w, 0.f);
      r1.x = fmaxf(a1.x + bq1.x, 0.f);
      r1.y = fmaxf(a1.y + bq1.y, 0.f);
      r1.z = fmaxf(a1.z + bq1.z, 0.f);
      r1.w = fmaxf(a1.w + bq1.w, 0.f);
      *(float4*)&H[(long)d * 64 + q * 8] = r0;
      *(float4*)&H[(long)d * 64 + q * 8 + 4] = r1;
    }
  }
}

// Fused: per-graph max-pool over kept nodes -> MLP head -> out[grp][:]
__global__ __launch_bounds__(256) void k_pool_head(
    const float* __restrict__ H, const float* __restrict__ maskf,
    const int* __restrict__ gs, const int* __restrict__ ge,
    const float* __restrict__ fw1, const float* __restrict__ fb1,
    const float* __restrict__ fw2, const float* __restrict__ fb2,
    float* __restrict__ out, int N, int C) {
  __shared__ float sP[4][64];
  __shared__ float sg[64];
  __shared__ float sg2[64];
  const int grp = blockIdx.x;
  const int lane = threadIdx.x & 63, wid = threadIdx.x >> 6;
  const int s = gs[grp], e = ge[grp];
  float v = 0.f;
  if (s <= e) {
    for (int i = s + wid; i <= e; i += 4)
      if (maskf[i] != 0.f) v = fmaxf(v, H[(long)i * 64 + lane]);
  }
  sP[wid][lane] = v;
  __syncthreads();
  if (wid == 0)
    sg[lane] = fmaxf(fmaxf(sP[0][lane], sP[1][lane]), fmaxf(sP[2][lane], sP[3][lane]));
  __syncthreads();
  if (threadIdx.x < 64) {
    const int f = threadIdx.x;
    float acc = fb1[f];
#pragma unroll 8
    for (int k = 0; k < 64; ++k) acc = fmaf(sg[k], fw1[k * 64 + f], acc);
    sg2[f] = fmaxf(acc, 0.f);
  }
  __syncthreads();
  if (threadIdx.x < C) {
    const int c = threadIdx.x;
    float acc = fb2[c];
#pragma unroll 8
    for (int k = 0; k < 64; ++k) acc = fmaf(sg2[k], fw2[k * C + c], acc);
    out[grp * C + c] = acc;
  }
}

extern "C" void kernel_launch(void* const* d_in, const int* in_sizes, int n_in,
                              void* d_out, int out_size, void* d_ws, size_t ws_size,
                              hipStream_t stream) {
  const float* x    = (const float*)d_in[0];
  const int*   ei   = (const int*)d_in[1];
  const int*   batch= (const int*)d_in[2];
  const void*  mraw = d_in[3];
  const float* W1   = (const float*)d_in[4];
  const float* b1   = (const float*)d_in[5];
  const float* W2   = (const float*)d_in[6];
  const float* b2   = (const float*)d_in[7];
  const float* W3   = (const float*)d_in[8];
  const float* b3   = (const float*)d_in[9];
  const float* fw1  = (const float*)d_in[10];
  const float* fb1  = (const float*)d_in[11];
  const float* fw2  = (const float*)d_in[12];
  const float* fb2  = (const float*)d_in[13];
  float* out = (float*)d_out;

  const int N = in_sizes[0] / 64;
  const int E = in_sizes[1] / 2;
  const int C = in_sizes[13];
  const int* src = ei;
  const int* dst = ei + E;
  const int G = out_size / C;

  char* ws = (char*)d_ws;
  size_t off_b = 0;
  auto alloc = [&](size_t bytes) -> void* {
    void* p = ws + off_b;
    off_b += (bytes + 255) & ~(size_t)255;
    return p;
  };
  int*    flag   = (int*)alloc(sizeof(int));
  float*  maskf  = (float*)alloc((size_t)N * 4);
  int*    cnt    = (int*)alloc((size_t)N * 4);
  float*  dinv   = (float*)alloc((size_t)N * 4);
  int*    off    = (int*)alloc((size_t)N * 4);
  int*    cursor = (int*)alloc((size_t)N * 4);
  int*    bsum   = (int*)alloc(256 * 4);
  int*    gs     = (int*)alloc((size_t)G * 4);
  int*    ge     = (int*)alloc((size_t)G * 4);
  int2*   offcnt = (int2*)alloc((size_t)N * 8);
  int2*   csr    = (int2*)alloc(((size_t)E + N) * 8);
  __half* T      = (__half*)alloc((size_t)N * 64 * 2);
  float*  HA     = (float*)alloc((size_t)N * 64 * 4);
  float*  HB     = (float*)alloc((size_t)N * 64 * 4);
  (void)ws_size;

  const int nb = (N + 255) / 256;

  k_detect<<<1, 1024, 0, stream>>>((const unsigned int*)mraw, N / 4, flag);
  k_prep<<<nb, 256, 0, stream>>>(mraw, flag, maskf, cnt, gs, ge, N, G);
  k_cnt<<<(E + 255) / 256, 256, 0, stream>>>(src, dst, maskf, cnt, E);
  k_scan1<<<nb, 256, 0, stream>>>(cnt, maskf, dinv, off, cursor, bsum, N);
  k_scan3<<<nb, 256, 0, stream>>>(off, bsum, nb, cursor, offcnt, csr, dinv,
                                  batch, gs, ge, N);
  k_fill<<<(E + 255) / 256, 256, 0, stream>>>(src, dst, dinv, cursor, csr, E);

  const int gemm_blocks = 2048;
  const int agg_blocks = 2048;
  // layer 1  (x used directly: dropped rows skipped, kept rows have mask=1)
  k_gemm<<<gemm_blocks, 256, 0, stream>>>(x, dinv, W1, T, N);
  k_agg<<<agg_blocks, 256, 0, stream>>>(T, offcnt, csr, b1, HA, N);
  // layer 2
  k_gemm<<<gemm_blocks, 256, 0, stream>>>(HA, dinv, W2, T, N);
  k_agg<<<agg_blocks, 256, 0, stream>>>(T, offcnt, csr, b2, HB, N);
  // layer 3
  k_gemm<<<gemm_blocks, 256, 0, stream>>>(HB, dinv, W3, T, N);
  k_agg<<<agg_blocks, 256, 0, stream>>>(T, offcnt, csr, b3, HA, N);

  k_pool_head<<<G, 256, 0, stream>>>(HA, maskf, gs, ge, fw1, fb1, fw2, fb2, out, N, C);
}

// Round 10
// 178.113 us; speedup vs baseline: 1.6316x; 1.5170x over previous
//
#include <hip/hip_runtime.h>
#include <hip/hip_fp16.h>

// ---------------------------------------------------------------------------
// GCN pipeline v10: MFMA dense GEMM (fp16 in, f32 acc) + light CSR gather.
// N=50000 nodes, E=800000 edges, H=F=64, G=512 graphs, C=10 classes
// ---------------------------------------------------------------------------

using half8 = __attribute__((ext_vector_type(8))) _Float16;
using f32x4 = __attribute__((ext_vector_type(4))) float;

// Single-block: detect whether mask is bytes (some word >1) or int32 0/1.
__global__ void k_detect(const unsigned int* __restrict__ m, int n_ints,
                         int* __restrict__ flag) {
  __shared__ int found;
  if (threadIdx.x == 0) found = 0;
  __syncthreads();
  int loc = 0;
  for (int i = threadIdx.x; i < n_ints; i += blockDim.x)
    if (m[i] > 1u) loc = 1;
  if (loc) found = 1;
  __syncthreads();
  if (threadIdx.x == 0) *flag = found;
}

// maskf + zero cnt + init gs/ge + x->fp16 + W1/2/3 -> MFMA-swizzled fp16.
// Wsw layout per layer: frag f = ks*4+ct (ks=k-step, ct=col-tile), lane l,
// j=0..7:  Wsw[layer][f*512 + l*8 + j] = W[ks*32+(l>>4)*8+j][ct*16+(l&15)]
__global__ void k_prep(const float* __restrict__ x, __half* __restrict__ xh,
                       const void* __restrict__ mraw, const int* __restrict__ flag,
                       float* __restrict__ maskf, int* __restrict__ cnt,
                       int* __restrict__ gs, int* __restrict__ ge,
                       const float* __restrict__ W1, const float* __restrict__ W2,
                       const float* __restrict__ W3, __half* __restrict__ Wsw,
                       long total, int N, int G) {
  long idx = (long)blockIdx.x * blockDim.x + threadIdx.x;
  if (idx < total) xh[idx] = __float2half_rn(x[idx]);
  if (idx < 3 * 4096) {
    const int layer = (int)(idx >> 12);
    const int rem = (int)(idx & 4095);
    const int f = rem >> 9;
    const int l = (rem >> 3) & 63;
    const int j = rem & 7;
    const int k = (f >> 2) * 32 + ((l >> 4) << 3) + j;
    const int c = ((f & 3) << 4) + (l & 15);
    const float* Wl = (layer == 0) ? W1 : (layer == 1) ? W2 : W3;
    Wsw[idx] = __float2half_rn(Wl[k * 64 + c]);
  }
  if (idx < G) { gs[idx] = 0x7fffffff; ge[idx] = -1; }
  if (idx < N) {
    float v;
    if (*flag) v = (float)((const unsigned char*)mraw)[idx];
    else       v = (float)((const int*)mraw)[idx];
    maskf[idx] = v;
    cnt[idx] = 0;
  }
}

// cnt[d] += 1 for each edge with both endpoints kept
__global__ void k_cnt(const int* __restrict__ src, const int* __restrict__ dst,
                      const float* __restrict__ maskf, int* __restrict__ cnt, int E) {
  int e = blockIdx.x * blockDim.x + threadIdx.x;
  if (e >= E) return;
  int s = src[e], d = dst[e];
  if (maskf[s] != 0.f && maskf[d] != 0.f) atomicAdd(&cnt[d], 1);
}

// dinv + slots(=cnt+kept) block-local scan; slots stashed in cursor[]
__global__ void k_scan1(const int* __restrict__ cnt, const float* __restrict__ maskf,
                        float* __restrict__ dinv, int* __restrict__ off,
                        int* __restrict__ cursor, int* __restrict__ bsum, int N) {
  __shared__ int s[256];
  int i = blockIdx.x * 256 + threadIdx.x;
  int c = (i < N) ? cnt[i] : 0;
  float mk = (i < N) ? maskf[i] : 0.f;
  float dsum = (float)c + mk;
  if (i < N) dinv[i] = (dsum > 0.f) ? rsqrtf(dsum) : 0.f;
  int v = c + (mk != 0.f ? 1 : 0);  // slots incl. self-loop
  if (i < N) cursor[i] = v;         // stash slots
  s[threadIdx.x] = v;
  __syncthreads();
#pragma unroll
  for (int d = 1; d < 256; d <<= 1) {
    int t = (threadIdx.x >= d) ? s[threadIdx.x - d] : 0;
    __syncthreads();
    s[threadIdx.x] += t;
    __syncthreads();
  }
  if (i < N) off[i] = s[threadIdx.x] - v;
  if (threadIdx.x == 255) bsum[blockIdx.x] = s[255];
}

// finalize offsets; offcnt=(off,slots); self-loop CSR entry; cursor; bounds.
__global__ void k_scan3(const int* __restrict__ off_loc, const int* __restrict__ bsum,
                        int nb, int* __restrict__ cursor, int2* __restrict__ offcnt,
                        int2* __restrict__ csr, const float* __restrict__ dinv,
                        const int* __restrict__ batch,
                        int* __restrict__ gs, int* __restrict__ ge, int N) {
  __shared__ int s[256];
  __shared__ int prefix;
  int v = (threadIdx.x < nb) ? bsum[threadIdx.x] : 0;
  s[threadIdx.x] = v;
  __syncthreads();
#pragma unroll
  for (int d = 1; d < 256; d <<= 1) {
    int t = (threadIdx.x >= d) ? s[threadIdx.x - d] : 0;
    __syncthreads();
    s[threadIdx.x] += t;
    __syncthreads();
  }
  if (threadIdx.x == blockIdx.x) prefix = s[threadIdx.x] - v;  // exclusive
  __syncthreads();
  int i = blockIdx.x * 256 + threadIdx.x;
  if (i >= N) return;
  int o = off_loc[i] + prefix;
  int slots = cursor[i];  // stashed by scan1
  offcnt[i] = make_int2(o, slots);
  float di = dinv[i];
  if (di != 0.f) {
    csr[o] = make_int2(i, __float_as_int(di * di));  // self-loop entry
    cursor[i] = o + 1;
  } else {
    cursor[i] = o;
  }
  int b = batch[i];
  if (i == 0 || batch[i - 1] != b) gs[b] = i;
  if (i == N - 1 || batch[i + 1] != b) ge[b] = i;
}

// Fill CSR: (src, weight) per kept edge, grouped by dst.
__global__ void k_fill(const int* __restrict__ src, const int* __restrict__ dst,
                       const float* __restrict__ dinv, int* __restrict__ cursor,
                       int2* __restrict__ csr, int E) {
  int e = blockIdx.x * blockDim.x + threadIdx.x;
  if (e >= E) return;
  int s = src[e], d = dst[e];
  float ws = dinv[s], wd = dinv[d];
  if (ws != 0.f && wd != 0.f) {
    int p = atomicAdd(&cursor[d], 1);
    csr[p] = make_int2(s, __float_as_int(ws * wd));
  }
}

// T = A @ W via MFMA 16x16x32 fp16. Wave per 16-row tile (grid-stride).
// A fp16 row-major [N][64]; Wsw pre-swizzled B-fragments (8 x half8 per lane).
template <bool HALFOUT>
__global__ __launch_bounds__(256) void k_gemm_mfma(const __half* __restrict__ A,
                                                   const __half* __restrict__ Wsw,
                                                   void* __restrict__ out, int N) {
  const int lane = threadIdx.x & 63;
  const int wid = threadIdx.x >> 6;
  half8 bfrag[8];
#pragma unroll
  for (int f = 0; f < 8; ++f)
    bfrag[f] = *(const half8*)&Wsw[f * 512 + lane * 8];
  const int tiles = (N + 15) >> 4;
  const int arow_off = ((lane >> 4) << 3);
  for (int t = blockIdx.x * 4 + wid; t < tiles; t += gridDim.x * 4) {
    const int rt = t << 4;
    int arow = rt + (lane & 15);
    if (arow >= N) arow = N - 1;
    const half8 a0 = *(const half8*)&A[(long)arow * 64 + arow_off];
    const half8 a1 = *(const half8*)&A[(long)arow * 64 + 32 + arow_off];
    f32x4 acc0 = {0.f, 0.f, 0.f, 0.f};
    f32x4 acc1 = {0.f, 0.f, 0.f, 0.f};
    f32x4 acc2 = {0.f, 0.f, 0.f, 0.f};
    f32x4 acc3 = {0.f, 0.f, 0.f, 0.f};
    acc0 = __builtin_amdgcn_mfma_f32_16x16x32_f16(a0, bfrag[0], acc0, 0, 0, 0);
    acc1 = __builtin_amdgcn_mfma_f32_16x16x32_f16(a0, bfrag[1], acc1, 0, 0, 0);
    acc2 = __builtin_amdgcn_mfma_f32_16x16x32_f16(a0, bfrag[2], acc2, 0, 0, 0);
    acc3 = __builtin_amdgcn_mfma_f32_16x16x32_f16(a0, bfrag[3], acc3, 0, 0, 0);
    acc0 = __builtin_amdgcn_mfma_f32_16x16x32_f16(a1, bfrag[4], acc0, 0, 0, 0);
    acc1 = __builtin_amdgcn_mfma_f32_16x16x32_f16(a1, bfrag[5], acc1, 0, 0, 0);
    acc2 = __builtin_amdgcn_mfma_f32_16x16x32_f16(a1, bfrag[6], acc2, 0, 0, 0);
    acc3 = __builtin_amdgcn_mfma_f32_16x16x32_f16(a1, bfrag[7], acc3, 0, 0, 0);
    const int col = lane & 15;
    const int mbase = rt + ((lane >> 4) << 2);
#pragma unroll
    for (int reg = 0; reg < 4; ++reg) {
      const int r = mbase + reg;
      if (r < N) {
        if (HALFOUT) {
          __half* o = (__half*)out + (long)r * 64 + col;
          o[0]  = __float2half_rn(acc0[reg]);
          o[16] = __float2half_rn(acc1[reg]);
          o[32] = __float2half_rn(acc2[reg]);
          o[48] = __float2half_rn(acc3[reg]);
        } else {
          float* o = (float*)out + (long)r * 64 + col;
          o[0]  = acc0[reg];
          o[16] = acc1[reg];
          o[32] = acc2[reg];
          o[48] = acc3[reg];
        }
      }
    }
  }
}

// H[d][:] = relu( sum_{e in csr[d]} w_e * T[src_e][:] + b )   (f32 out)
// Wave per kept node; 8 edges/iter via 8-lane groups; tiny epilogue.
__global__ __launch_bounds__(256) void k_agg(const __half* __restrict__ Th,
                                             const int2* __restrict__ offcnt,
                                             const int2* __restrict__ csr,
                                             const float* __restrict__ b,
                                             float* __restrict__ H, int N) {
  const int lane = threadIdx.x & 63;
  const int wid = threadIdx.x >> 6;
  const int grp = lane >> 3;   // which edge of the octet
  const int q = lane & 7;      // column group: cols 8q..8q+7
  const __half* __restrict__ Tq = Th + q * 8;
  const float4 bq0 = *(const float4*)&b[q * 8];
  const float4 bq1 = *(const float4*)&b[q * 8 + 4];

  for (int d = blockIdx.x * 4 + wid; d < N; d += gridDim.x * 4) {
    const int2 oc = offcnt[d];
    const int n = oc.y;
    if (n == 0) continue;  // dropped node
    float4 a0 = make_float4(0.f, 0.f, 0.f, 0.f);
    float4 a1 = make_float4(0.f, 0.f, 0.f, 0.f);
    int done = 0;
    while (done < n) {
      const int chunk = min(n - done, 64);
      int2 ce = (lane < chunk) ? csr[oc.x + done + lane] : make_int2(0, 0);
      const int rounds = (chunk + 7) & ~7;
#pragma unroll 2
      for (int i = 0; i < rounds; i += 8) {
        const int j = i + grp;
        const int s = __shfl(ce.x, j);
        const float w = __int_as_float(__shfl(ce.y, j));  // 0 for padded lanes
        const float4 raw = *(const float4*)&Tq[(long)s * 64];
        const __half2* hp = (const __half2*)&raw;
        const float2 f0 = __half22float2(hp[0]);
        const float2 f1 = __half22float2(hp[1]);
        const float2 f2 = __half22float2(hp[2]);
        const float2 f3 = __half22float2(hp[3]);
        a0.x = fmaf(f0.x, w, a0.x);
        a0.y = fmaf(f0.y, w, a0.y);
        a0.z = fmaf(f1.x, w, a0.z);
        a0.w = fmaf(f1.y, w, a0.w);
        a1.x = fmaf(f2.x, w, a1.x);
        a1.y = fmaf(f2.y, w, a1.y);
        a1.z = fmaf(f3.x, w, a1.z);
        a1.w = fmaf(f3.y, w, a1.w);
      }
      done += chunk;
    }
    // butterfly across the 8 edge-groups
#pragma unroll
    for (int m = 8; m <= 32; m <<= 1) {
      a0.x += __shfl_xor(a0.x, m);
      a0.y += __shfl_xor(a0.y, m);
      a0.z += __shfl_xor(a0.z, m);
      a0.w += __shfl_xor(a0.w, m);
      a1.x += __shfl_xor(a1.x, m);
      a1.y += __shfl_xor(a1.y, m);
      a1.z += __shfl_xor(a1.z, m);
      a1.w += __shfl_xor(a1.w, m);
    }
    if (grp == 0) {
      float4 r0, r1;
      r0.x = fmaxf(a0.x + bq0.x, 0.f);
      r0.y = fmaxf(a0.y + bq0.y, 0.f);
      r0.z = fmaxf(a0.z + bq0.z, 0.f);
      r0.w = fmaxf(a0.w + bq0.w, 0.f);
      r1.x = fmaxf(a1.x + bq1.x, 0.f);
      r1.y = fmaxf(a1.y + bq1.y, 0.f);
      r1.z = fmaxf(a1.z + bq1.z, 0.f);
      r1.w = fmaxf(a1.w + bq1.w, 0.f);
      *(float4*)&H[(long)d * 64 + q * 8] = r0;
      *(float4*)&H[(long)d * 64 + q * 8 + 4] = r1;
    }
  }
}

// Same as k_agg but writes fp16 (feeds next layer's MFMA GEMM).
__global__ __launch_bounds__(256) void k_agg_h(const __half* __restrict__ Th,
                                               const int2* __restrict__ offcnt,
                                               const int2* __restrict__ csr,
                                               const float* __restrict__ b,
                                               __half* __restrict__ H, int N) {
  const int lane = threadIdx.x & 63;
  const int wid = threadIdx.x >> 6;
  const int grp = lane >> 3;
  const int q = lane & 7;
  const __half* __restrict__ Tq = Th + q * 8;
  const float4 bq0 = *(const float4*)&b[q * 8];
  const float4 bq1 = *(const float4*)&b[q * 8 + 4];

  for (int d = blockIdx.x * 4 + wid; d < N; d += gridDim.x * 4) {
    const int2 oc = offcnt[d];
    const int n = oc.y;
    if (n == 0) continue;
    float4 a0 = make_float4(0.f, 0.f, 0.f, 0.f);
    float4 a1 = make_float4(0.f, 0.f, 0.f, 0.f);
    int done = 0;
    while (done < n) {
      const int chunk = min(n - done, 64);
      int2 ce = (lane < chunk) ? csr[oc.x + done + lane] : make_int2(0, 0);
      const int rounds = (chunk + 7) & ~7;
#pragma unroll 2
      for (int i = 0; i < rounds; i += 8) {
        const int j = i + grp;
        const int s = __shfl(ce.x, j);
        const float w = __int_as_float(__shfl(ce.y, j));
        const float4 raw = *(const float4*)&Tq[(long)s * 64];
        const __half2* hp = (const __half2*)&raw;
        const float2 f0 = __half22float2(hp[0]);
        const float2 f1 = __half22float2(hp[1]);
        const float2 f2 = __half22float2(hp[2]);
        const float2 f3 = __half22float2(hp[3]);
        a0.x = fmaf(f0.x, w, a0.x);
        a0.y = fmaf(f0.y, w, a0.y);
        a0.z = fmaf(f1.x, w, a0.z);
        a0.w = fmaf(f1.y, w, a0.w);
        a1.x = fmaf(f2.x, w, a1.x);
        a1.y = fmaf(f2.y, w, a1.y);
        a1.z = fmaf(f3.x, w, a1.z);
        a1.w = fmaf(f3.y, w, a1.w);
      }
      done += chunk;
    }
#pragma unroll
    for (int m = 8; m <= 32; m <<= 1) {
      a0.x += __shfl_xor(a0.x, m);
      a0.y += __shfl_xor(a0.y, m);
      a0.z += __shfl_xor(a0.z, m);
      a0.w += __shfl_xor(a0.w, m);
      a1.x += __shfl_xor(a1.x, m);
      a1.y += __shfl_xor(a1.y, m);
      a1.z += __shfl_xor(a1.z, m);
      a1.w += __shfl_xor(a1.w, m);
    }
    if (grp == 0) {
      __half2 h0 = __floats2half2_rn(fmaxf(a0.x + bq0.x, 0.f), fmaxf(a0.y + bq0.y, 0.f));
      __half2 h1 = __floats2half2_rn(fmaxf(a0.z + bq0.z, 0.f), fmaxf(a0.w + bq0.w, 0.f));
      __half2 h2 = __floats2half2_rn(fmaxf(a1.x + bq1.x, 0.f), fmaxf(a1.y + bq1.y, 0.f));
      __half2 h3 = __floats2half2_rn(fmaxf(a1.z + bq1.z, 0.f), fmaxf(a1.w + bq1.w, 0.f));
      __half2* o = (__half2*)&H[(long)d * 64 + q * 8];
      o[0] = h0; o[1] = h1; o[2] = h2; o[3] = h3;
    }
  }
}

// Fused: per-graph max-pool over kept nodes -> MLP head -> out[grp][:]
__global__ __launch_bounds__(256) void k_pool_head(
    const float* __restrict__ H, const float* __restrict__ maskf,
    const int* __restrict__ gs, const int* __restrict__ ge,
    const float* __restrict__ fw1, const float* __restrict__ fb1,
    const float* __restrict__ fw2, const float* __restrict__ fb2,
    float* __restrict__ out, int N, int C) {
  __shared__ float sP[4][64];
  __shared__ float sg[64];
  __shared__ float sg2[64];
  const int grp = blockIdx.x;
  const int lane = threadIdx.x & 63, wid = threadIdx.x >> 6;
  const int s = gs[grp], e = ge[grp];
  float v = 0.f;
  if (s <= e) {
    for (int i = s + wid; i <= e; i += 4)
      if (maskf[i] != 0.f) v = fmaxf(v, H[(long)i * 64 + lane]);
  }
  sP[wid][lane] = v;
  __syncthreads();
  if (wid == 0)
    sg[lane] = fmaxf(fmaxf(sP[0][lane], sP[1][lane]), fmaxf(sP[2][lane], sP[3][lane]));
  __syncthreads();
  if (threadIdx.x < 64) {
    const int f = threadIdx.x;
    float acc = fb1[f];
#pragma unroll 8
    for (int k = 0; k < 64; ++k) acc = fmaf(sg[k], fw1[k * 64 + f], acc);
    sg2[f] = fmaxf(acc, 0.f);
  }
  __syncthreads();
  if (threadIdx.x < C) {
    const int c = threadIdx.x;
    float acc = fb2[c];
#pragma unroll 8
    for (int k = 0; k < 64; ++k) acc = fmaf(sg2[k], fw2[k * C + c], acc);
    out[grp * C + c] = acc;
  }
}

extern "C" void kernel_launch(void* const* d_in, const int* in_sizes, int n_in,
                              void* d_out, int out_size, void* d_ws, size_t ws_size,
                              hipStream_t stream) {
  const float* x    = (const float*)d_in[0];
  const int*   ei   = (const int*)d_in[1];
  const int*   batch= (const int*)d_in[2];
  const void*  mraw = d_in[3];
  const float* W1   = (const float*)d_in[4];
  const float* b1   = (const float*)d_in[5];
  const float* W2   = (const float*)d_in[6];
  const float* b2   = (const float*)d_in[7];
  const float* W3   = (const float*)d_in[8];
  const float* b3   = (const float*)d_in[9];
  const float* fw1  = (const float*)d_in[10];
  const float* fb1  = (const float*)d_in[11];
  const float* fw2  = (const float*)d_in[12];
  const float* fb2  = (const float*)d_in[13];
  float* out = (float*)d_out;

  const int N = in_sizes[0] / 64;
  const int E = in_sizes[1] / 2;
  const int C = in_sizes[13];
  const int* src = ei;
  const int* dst = ei + E;
  const int G = out_size / C;

  char* ws = (char*)d_ws;
  size_t off_b = 0;
  auto alloc = [&](size_t bytes) -> void* {
    void* p = ws + off_b;
    off_b += (bytes + 255) & ~(size_t)255;
    return p;
  };
  int*    flag   = (int*)alloc(sizeof(int));
  float*  maskf  = (float*)alloc((size_t)N * 4);
  int*    cnt    = (int*)alloc((size_t)N * 4);
  float*  dinv   = (float*)alloc((size_t)N * 4);
  int*    off    = (int*)alloc((size_t)N * 4);
  int*    cursor = (int*)alloc((size_t)N * 4);
  int*    bsum   = (int*)alloc(256 * 4);
  int*    gs     = (int*)alloc((size_t)G * 4);
  int*    ge     = (int*)alloc((size_t)G * 4);
  int2*   offcnt = (int2*)alloc((size_t)N * 8);
  int2*   csr    = (int2*)alloc(((size_t)E + N) * 8);
  __half* Wsw    = (__half*)alloc(3 * 4096 * 2);
  __half* xh     = (__half*)alloc((size_t)N * 64 * 2);
  __half* T      = (__half*)alloc((size_t)N * 64 * 2);
  __half* H1h    = (__half*)alloc((size_t)N * 64 * 2);
  __half* H2h    = (__half*)alloc((size_t)N * 64 * 2);
  float*  H3     = (float*)alloc((size_t)N * 64 * 4);
  (void)ws_size;

  const int nb = (N + 255) / 256;
  const long total = (long)N * 64;
  const int prep_blocks = (int)((total + 255) / 256);

  k_detect<<<1, 1024, 0, stream>>>((const unsigned int*)mraw, N / 4, flag);
  k_prep<<<prep_blocks, 256, 0, stream>>>(x, xh, mraw, flag, maskf, cnt, gs, ge,
                                          W1, W2, W3, Wsw, total, N, G);
  k_cnt<<<(E + 255) / 256, 256, 0, stream>>>(src, dst, maskf, cnt, E);
  k_scan1<<<nb, 256, 0, stream>>>(cnt, maskf, dinv, off, cursor, bsum, N);
  k_scan3<<<nb, 256, 0, stream>>>(off, bsum, nb, cursor, offcnt, csr, dinv,
                                  batch, gs, ge, N);
  k_fill<<<(E + 255) / 256, 256, 0, stream>>>(src, dst, dinv, cursor, csr, E);

  const int gemm_blocks = 512;
  const int agg_blocks = 2048;
  // layer 1
  k_gemm_mfma<true><<<gemm_blocks, 256, 0, stream>>>(xh, Wsw, T, N);
  k_agg_h<<<agg_blocks, 256, 0, stream>>>(T, offcnt, csr, b1, H1h, N);
  // layer 2
  k_gemm_mfma<true><<<gemm_blocks, 256, 0, stream>>>(H1h, Wsw + 4096, T, N);
  k_agg_h<<<agg_blocks, 256, 0, stream>>>(T, offcnt, csr, b2, H2h, N);
  // layer 3
  k_gemm_mfma<true><<<gemm_blocks, 256, 0, stream>>>(H2h, Wsw + 8192, T, N);
  k_agg<<<agg_blocks, 256, 0, stream>>>(T, offcnt, csr, b3, H3, N);

  k_pool_head<<<G, 256, 0, stream>>>(H3, maskf, gs, ge, fw1, fb1, fw2, fb2, out, N, C);
}